// Round 11
// baseline (54.787 us; speedup 1.0000x reference)
//
#include <hip/hip_runtime.h>
#include <hip/hip_bf16.h>

typedef __attribute__((ext_vector_type(8))) short short8;
typedef __attribute__((ext_vector_type(4))) float f32x4;
typedef __attribute__((ext_vector_type(2))) unsigned int uint2v;
typedef float f4a __attribute__((ext_vector_type(4), aligned(4)));

constexpr int NF = 169;
constexpr int NH = 128;

#define MFMA(a, b, c) __builtin_amdgcn_mfma_f32_16x16x32_bf16(a, b, c, 0, 0, 0)

__device__ inline unsigned short f2bf(float f) {
    union { __hip_bfloat16 h; unsigned short u; } c;
    c.h = __float2bfloat16(f);
    return c.u;
}
__device__ inline float bf2f(unsigned short u) {
    union { unsigned int u; float f; } c;
    c.u = ((unsigned int)u) << 16;
    return c.f;
}

// Block barrier draining only the LDS pipe (cross-wave deps here are LDS-only;
// global stores stay in flight — no vmcnt drain).
__device__ inline void block_sync_lds() {
    __builtin_amdgcn_sched_barrier(0);
    asm volatile("s_waitcnt lgkmcnt(0)" ::: "memory");
    __builtin_amdgcn_sched_barrier(0);
    __builtin_amdgcn_s_barrier();
    __builtin_amdgcn_sched_barrier(0);
}

// Intra-wave producer->consumer fence for LDS (validated pattern from v5/v6).
#define WVFENCE() do { \
    asm volatile("s_waitcnt lgkmcnt(0)" ::: "memory"); \
    __builtin_amdgcn_wave_barrier(); \
} while (0)

// pool_sub<S>: given a staged row (slot layout in xt), compute windows 9S..9S+8.
// Phase A (S=0,1): slots s hold k = s*8      (slots 0..12 = k0..103)
// Phase B (S=2,3): slots s hold k = 80 + s*8 (slots 0..11 = k80..175)
template<int S>
__device__ inline void pool_sub(const unsigned short* __restrict__ xrow, float* pw) {
    constexpr int S0 = (S == 0) ? 0 : (S == 1) ? 3 : (S == 2) ? 0 : 4;   // first slot
    constexpr int S1 = (S == 0) ? 8 : (S == 1) ? 12 : (S == 2) ? 9 : 11; // last slot
    constexpr int KBASE = (S <= 1) ? (S0 * 8) : (80 + S0 * 8);
    constexpr int NSL = S1 - S0 + 1;
    float fl[NSL * 8];
    #pragma unroll
    for (int s = 0; s < NSL; ++s) {
        short8 v = *(const short8*)(xrow + (S0 + s) * 8);
        #pragma unroll
        for (int j = 0; j < 8; ++j) fl[s * 8 + j] = bf2f((unsigned short)v[j]);
    }
    #pragma unroll
    for (int t = 0; t < 9; ++t) {
        const int w = 9 * S + t;
        const int wi = w / 6, wj = w % 6;      // compile-time
        float s = 0.0f;
        #pragma unroll
        for (int rr = 0; rr < 3; ++rr)
            #pragma unroll
            for (int cc = 0; cc < 3; ++cc) {
                const int gi = (2 * wi + rr) * 14 + 2 * wj + cc;  // compile-time
                if (gi < NF) s += fl[gi - KBASE];                  // pad -> 0
            }
        pw[t] = fmaxf(s * (1.0f / 9.0f), 0.0f);
    }
}

template<int S>
__device__ inline void store9(unsigned short* __restrict__ pool_g, int grow, const float* pw) {
    #pragma unroll
    for (int t = 0; t < 9; ++t) {
        const int k = 9 * S + t;               // compile-time
        pool_g[((k >> 3) * 256 + grow) * 8 + (k & 7)] = f2bf(pw[t]);
    }
}

// LDS map (78336 B, 2 blocks/CU):
//  [0, 32768):      pool_g[8][256][8] bf16        (later h_g groups 0..7)
//  [32768, 59392):  xt[4 waves][32 rows][104] bf16 (wave-private staging; later h_g upper)
//  [0, 65536):      h_g[16][256][8] bf16 after GEMM1 (aliases pool_g + xt)
//  [65536, 77824):  w1g[8][128][8] bf16; stage[16][169] f32 aliases after GEMM1
//  [77824, 78336):  b1s[128] f32
__global__ __launch_bounds__(256, 2) void fused_v11(
    const float* __restrict__ x,
    const float* __restrict__ w1,
    const float* __restrict__ b1,
    const float* __restrict__ w2,
    const float* __restrict__ b2,
    float* __restrict__ out)
{
    __shared__ __align__(16) char smem[78336];
    unsigned short* pool_g = (unsigned short*)smem;            // [8][256][8]
    unsigned short* h_g    = (unsigned short*)smem;            // [16][256][8]
    unsigned short* w1g    = (unsigned short*)(smem + 65536);  // [8][128][8]
    float*          stage  = (float*)(smem + 65536);           // [16][169]
    float*          b1s    = (float*)(smem + 77824);           // [128]

    const int tid  = threadIdx.x;
    const int wid  = tid >> 6;
    const int lane = tid & 63;
    const int lr   = lane & 15;
    const int hi   = lane >> 4;

    unsigned short* xt = (unsigned short*)(smem + 32768 + wid * 6656);  // [32][104]

    // ---------------- stage w1 -> w1g (bf16, k zero-padded 36->64), b1 -> b1s ----------------
    #pragma unroll
    for (int it = 0; it < 4; ++it) {
        const int idx = tid + it * 256;   // 0..1023 = n*8 + g
        const int n = idx >> 3, g = idx & 7;
        short8 pk;
        #pragma unroll
        for (int j = 0; j < 8; ++j) {
            const int k = g * 8 + j;
            pk[j] = (short)f2bf(k < 36 ? w1[n * 36 + k] : 0.0f);
        }
        *(short8*)(w1g + (g * 128 + n) * 8) = pk;
    }
    if (tid < 128) b1s[tid] = b1[tid];

    // ---------------- zero-fill this wave's pool_g pad (k=36..63, rows wid*64+lane) ----------
    {
        const int zrow = wid * 64 + lane;
        const short8 z8 = {0, 0, 0, 0, 0, 0, 0, 0};
        *(uint2v*)(pool_g + (4 * 256 + zrow) * 8 + 4) = (uint2v){0u, 0u};  // k36..39
        *(short8*)(pool_g + (5 * 256 + zrow) * 8) = z8;                    // k40..47
        *(short8*)(pool_g + (6 * 256 + zrow) * 8) = z8;                    // k48..55
        *(short8*)(pool_g + (7 * 256 + zrow) * 8) = z8;                    // k56..63
    }

    // ---------------- wave-private coalesced pooling (no block barriers) ----------------
    const long blkRowBase = (long)blockIdx.x * 256;
    const long rowBaseW   = blkRowBase + wid * 64;
    const int  srow = lane & 31;   // row within 32-row group
    const int  sub  = lane >> 5;   // 0: windows 0..8 / 18..26; 1: 9..17 / 27..35
    const unsigned short* xrow = xt + srow * 104;

    #pragma unroll 1
    for (int half = 0; half < 2; ++half) {
        const float* __restrict__ xsrc = x + (rowBaseW + half * 32) * NF;
        const int grow = wid * 64 + half * 32 + srow;

        // ---- phase A: stage chunks c=0..25 (k0..103) for 32 rows; coalesced ----
        #pragma unroll
        for (int i = 0; i < 13; ++i) {
            const int t = lane + i * 64;           // < 832 = 32*26 exactly
            const int r = t / 26, c = t - r * 26;
            f4a v = *(const f4a*)(xsrc + r * NF + c * 4);
            uint2v pk;
            pk.x = (unsigned)f2bf(v[0]) | ((unsigned)f2bf(v[1]) << 16);
            pk.y = (unsigned)f2bf(v[2]) | ((unsigned)f2bf(v[3]) << 16);
            *(uint2v*)(xt + r * 104 + c * 4) = pk;
        }
        WVFENCE();

        // windows 0..17 (window-rows 0..2), half-wave split
        {
            float pw[9];
            if (sub == 0) { pool_sub<0>(xrow, pw); store9<0>(pool_g, grow, pw); }
            else          { pool_sub<1>(xrow, pw); store9<1>(pool_g, grow, pw); }
        }
        WVFENCE();   // xt reads retired before phase B overwrites

        // ---- phase B: stage chunks c=20..42 (k80..171) into slots 0..11 ----
        #pragma unroll
        for (int i = 0; i < 12; ++i) {
            const int t = lane + i * 64;
            if (t < 736) {                          // 32*23
                const int r = t / 23, c = 20 + (t - r * 23);
                if (c < 42) {
                    f4a v = *(const f4a*)(xsrc + r * NF + c * 4);
                    uint2v pk;
                    pk.x = (unsigned)f2bf(v[0]) | ((unsigned)f2bf(v[1]) << 16);
                    pk.y = (unsigned)f2bf(v[2]) | ((unsigned)f2bf(v[3]) << 16);
                    *(uint2v*)(xt + r * 104 + (c - 20) * 4) = pk;
                } else {
                    const float v = xsrc[r * NF + 168];   // tail element k=168
                    *(unsigned int*)(xt + r * 104 + 88) = (unsigned)f2bf(v); // k168 + zero pad
                }
            }
        }
        WVFENCE();

        // windows 18..35 (window-rows 3..5)
        {
            float pw[9];
            if (sub == 0) { pool_sub<2>(xrow, pw); store9<2>(pool_g, grow, pw); }
            else          { pool_sub<3>(xrow, pw); store9<3>(pool_g, grow, pw); }
        }
        WVFENCE();   // pool writes visible; xt reusable for next half
    }

    // ---------------- A1 fragments (intra-wave rows) + w2/b2 fragments to registers ----------
    short8 afrag[4][2];
    #pragma unroll
    for (int mt = 0; mt < 4; ++mt)
        #pragma unroll
        for (int ks = 0; ks < 2; ++ks) {
            const int g = ks * 4 + hi;
            afrag[mt][ks] = *(const short8*)(pool_g + (g * 256 + wid * 64 + mt * 16 + lr) * 8);
        }

    const int nOt = (wid < 3) ? 3 : 2;   // ot = wid + 4t, 11 total
    short8 wfrag[3][4];
    float  bias2[3];
    #pragma unroll
    for (int t = 0; t < 3; ++t) {
        const int ot = wid + 4 * t;
        const int o  = ot * 16 + lr;
        const bool valid = (t < nOt) && (o < NF);
        bias2[t] = valid ? b2[o] : 0.0f;
        #pragma unroll
        for (int ks = 0; ks < 4; ++ks) {
            short8 pk = {0, 0, 0, 0, 0, 0, 0, 0};
            if (valid) {
                const float* wp = w2 + o * NH + ks * 32 + hi * 8;
                #pragma unroll
                for (int j = 0; j < 8; ++j) pk[j] = (short)f2bf(wp[j]);
            }
            wfrag[t][ks] = pk;
        }
    }
    block_sync_lds();   // (A) all pooling + afrag reads done -> h_g may overwrite

    // ---------------- GEMM1: h = relu(pooled @ w1^T + b1) -> h_g ----------------
    short8 b1f[8][2];
    #pragma unroll
    for (int nt = 0; nt < 8; ++nt)
        #pragma unroll
        for (int ks = 0; ks < 2; ++ks) {
            const int g = ks * 4 + hi;
            b1f[nt][ks] = *(const short8*)(w1g + (g * 128 + nt * 16 + lr) * 8);
        }
    float bias1[8];
    #pragma unroll
    for (int nt = 0; nt < 8; ++nt) bias1[nt] = b1s[nt * 16 + lr];

    #pragma unroll
    for (int mt = 0; mt < 4; ++mt) {
        #pragma unroll
        for (int nt = 0; nt < 8; ++nt) {
            f32x4 c = {0.f, 0.f, 0.f, 0.f};
            c = MFMA(afrag[mt][0], b1f[nt][0], c);
            c = MFMA(afrag[mt][1], b1f[nt][1], c);
            const int g = 2 * nt + (lr >> 3);
            const int e = lr & 7;
            #pragma unroll
            for (int r = 0; r < 4; ++r) {
                const float v = fmaxf(c[r] + bias1[nt], 0.0f);
                const int rw = wid * 64 + mt * 16 + hi * 4 + r;
                h_g[(g * 256 + rw) * 8 + e] = (unsigned short)f2bf(v);
            }
        }
    }
    block_sync_lds();   // (B) h_g complete; w1g dead -> stage usable

    // ---------------- GEMM2 (ot-split, w2 in regs) + staged coalesced stores ----------------
    #pragma unroll 1
    for (int mt = 0; mt < 16; ++mt) {
        short8 a2[4];
        #pragma unroll
        for (int ks = 0; ks < 4; ++ks) {
            const int g = ks * 4 + hi;
            a2[ks] = *(const short8*)(h_g + (g * 256 + mt * 16 + lr) * 8);
        }
        f32x4 acc[3];
        #pragma unroll
        for (int t = 0; t < 3; ++t) {
            f32x4 c = {0.f, 0.f, 0.f, 0.f};
            #pragma unroll
            for (int ks = 0; ks < 4; ++ks)
                c = MFMA(a2[ks], wfrag[t][ks], c);
            acc[t] = c;
        }
        #pragma unroll
        for (int t = 0; t < 3; ++t) {
            const int ot = wid + 4 * t;
            const int o  = ot * 16 + lr;
            if (t < nOt && o < NF) {
                #pragma unroll
                for (int r = 0; r < 4; ++r)
                    stage[(hi * 4 + r) * NF + o] = acc[t][r] + bias2[t];
            }
        }
        block_sync_lds();   // stage complete for this m-tile

        float* op = out + (blkRowBase + mt * 16) * NF;
        #pragma unroll
        for (int it = 0; it < 3; ++it) {
            const int i = tid + it * 256;
            if (i < 676) {                      // 16*169/4 float4s
                f32x4 v = *(const f32x4*)(stage + 4 * i);
                *(f32x4*)(op + 4 * i) = v;
            }
        }
        block_sync_lds();   // stage ds_reads drained; stores stay in flight
    }
}

extern "C" void kernel_launch(void* const* d_in, const int* in_sizes, int n_in,
                              void* d_out, int out_size, void* d_ws, size_t ws_size,
                              hipStream_t stream) {
    const float* x  = (const float*)d_in[0];
    const float* w1 = (const float*)d_in[1];
    const float* b1 = (const float*)d_in[2];
    const float* w2 = (const float*)d_in[3];
    const float* b2 = (const float*)d_in[4];
    float* out = (float*)d_out;

    const int rows = in_sizes[0] / NF;      // 131072
    const int blocks = rows / 256;          // 512
    fused_v11<<<blocks, 256, 0, stream>>>(x, w1, b1, w2, b2, out);
}